// Round 7
// baseline (149.937 us; speedup 1.0000x reference)
//
#include <hip/hip_runtime.h>
#include <hip/hip_bf16.h>

// QuIP#-style quantized linear. R7: same 32x32x16-MFMA decompress-GEMM as R6
// but the gather pipeline is sized to FIT the 128-VGPR budget (rolling
// buffers bfr[7][2]/iv[3]/areg[2][2] ~= 115 regs) and pinned with
// __builtin_amdgcn_sched_barrier(0) so the backend cannot sink the gathers
// back to their uses (R4/R5/R6 all got flattened: VGPR_Count 52/32/36).
// Target: ~220 gathers in flight/CU -> L2 request-service floor ~27-35 us.

typedef __attribute__((ext_vector_type(4))) float f32x4;
typedef __attribute__((ext_vector_type(16))) float f32x16;
typedef __attribute__((ext_vector_type(8))) __bf16 bf16x8;
typedef __attribute__((ext_vector_type(4))) __bf16 bf16x4;
typedef __attribute__((ext_vector_type(4))) int i32x4;

#define IN_F 8192
#define OUT_F 8192
#define TOKENS 32
#define KSPLIT 16
#define KCHUNK 512                 // k per block
#define NTILES (KCHUNK / 16)       // 32 mfma k-tiles per wave
#define NG (NTILES / 2)            // 16 groups of 2 tiles
#define DG 6                       // gather lookahead (groups)
#define DI 8                       // idx lookahead (groups)
#define BB (DG + 1)                // 7 rolling B-frag slots
#define BIV (DI - DG + 1)          // 3 rolling idx slots
#define CH (KCHUNK / 8)            // 64 8-elem chunks per token row in LDS
#define INV_SQRT_8192 0.011048543456039806f
#define PAD(i) ((i) + ((i) >> 5))

// ---------------- register FWHT-32 ----------------
__device__ inline void fwht32_reg(float* r) {
    #pragma unroll
    for (int h = 1; h < 32; h <<= 1)
        #pragma unroll
        for (int i = 0; i < 32; i += 2 * h)
            #pragma unroll
            for (int j = 0; j < h; ++j) {
                float a = r[i + j], b = r[i + j + h];
                r[i + j] = a + b;
                r[i + j + h] = a - b;
            }
}

// ---------------- full FWHT-8192 in padded LDS, 256 threads ----------------
__device__ inline void fwht8192_lds(float* s, int tid) {
    float r[32];
    int b1 = tid * 32;                       // pass 1: bits 0-4
    #pragma unroll
    for (int j = 0; j < 32; ++j) r[j] = s[PAD(b1 + j)];
    fwht32_reg(r);
    #pragma unroll
    for (int j = 0; j < 32; ++j) s[PAD(b1 + j)] = r[j];
    __syncthreads();
    int b2 = (tid & 31) + (tid >> 5) * 1024; // pass 2: bits 5-9
    #pragma unroll
    for (int j = 0; j < 32; ++j) r[j] = s[PAD(b2 + 32 * j)];
    fwht32_reg(r);
    #pragma unroll
    for (int j = 0; j < 32; ++j) s[PAD(b2 + 32 * j)] = r[j];
    __syncthreads();
    #pragma unroll
    for (int jj = 0; jj < 4; ++jj) {         // pass 3: bits 10-12
        float g[8];
        int b3 = tid * 4 + jj;
        #pragma unroll
        for (int k = 0; k < 8; ++k) g[k] = s[PAD(b3 + 1024 * k)];
        #pragma unroll
        for (int h = 1; h < 8; h <<= 1)
            #pragma unroll
            for (int i = 0; i < 8; i += 2 * h)
                #pragma unroll
                for (int j = 0; j < h; ++j) {
                    float a = g[i + j], b = g[i + j + h];
                    g[i + j] = a + b;
                    g[i + j + h] = a - b;
                }
        #pragma unroll
        for (int k = 0; k < 8; ++k) s[PAD(b3 + 1024 * k)] = g[k];
    }
    __syncthreads();
}

// ---------------- kernel 1: codebook cvt + input FWHT ----------------
__global__ __launch_bounds__(256)
void prep_kernel(const float* __restrict__ cb, __bf16* __restrict__ cbb,
                 const float* __restrict__ x, const float* __restrict__ su,
                 __bf16* __restrict__ xh) {
    __shared__ float s[8192 + 256];
    const int tid = threadIdx.x;
    if (blockIdx.x < 512) {
        int i = blockIdx.x * 256 + tid;
        float4 v = ((const float4*)cb)[i];
        bf16x4 o;
        o[0] = (__bf16)v.x; o[1] = (__bf16)v.y;
        o[2] = (__bf16)v.z; o[3] = (__bf16)v.w;
        ((bf16x4*)cbb)[i] = o;
        return;
    }
    const int t = blockIdx.x - 512;
    #pragma unroll
    for (int i = tid; i < IN_F; i += 256)
        s[PAD(i)] = x[t * IN_F + i] * su[i];
    __syncthreads();
    fwht8192_lds(s, tid);
    #pragma unroll
    for (int i = tid; i < IN_F; i += 256)
        xh[t * IN_F + i] = (__bf16)(s[PAD(i)] * INV_SQRT_8192);
}

// ---------------- kernel 2: zpart = xh @ W^T (bf16 partials) --------------
// 512 blocks (32 nb x 16 ks) x 512 thr (8 waves). Block = 256 n x 512 k.
// mfma_f32_32x32x16_bf16:
//   A[m=lane&31][k=8*(lane>>5)+j]  (xh from LDS, xor-swizzled)
//   B[k=8*(lane>>5)+j][n=lane&31]  = one 16B codebook entry per lane
//   D[m=(reg&3)+4*(lane>>5)+8*(reg>>2)][n=lane&31]
// Unified SW pipeline: at virtual iter v -> idx(v+DI), gathers(v+DG),
// a-frag ds_read(v+1), sched_barrier, consume(v). Rolling buffers fit 128
// VGPRs so the allocator keeps the loads hoisted.
__global__ __launch_bounds__(512, 4)
void qgemm_kernel(const int* __restrict__ qidxs,
                  const __bf16* __restrict__ cb,
                  const __bf16* __restrict__ xh,
                  __bf16* __restrict__ zpart) {
    __shared__ __align__(16) __bf16 xt[TOKENS * KCHUNK];   // 32 KB
    const int ks = blockIdx.x & 15;
    const int nb = blockIdx.x >> 4;
    const int tid = threadIdx.x;
    const int wave = tid >> 6, lane = tid & 63;
    const int h = lane >> 5, lc = lane & 31;
    const int n = nb * 256 + wave * 32 + lc;

    // stage xh k-slice (32 tok x 512 k) -> LDS, 16B chunks xor-swizzled
    #pragma unroll
    for (int i = 0; i < 4; ++i) {
        int f = i * 512 + tid, r = f >> 6, c = f & 63;
        i32x4 v = *(const i32x4*)(xh + (size_t)r * IN_F + ks * KCHUNK + c * 8);
        *(i32x4*)(xt + ((r * CH + (c ^ (r & 7))) << 3)) = v;
    }
    __syncthreads();    // the only barrier

    const int* qrow = qidxs + (size_t)n * (IN_F / 8) + ks * CH;
    const bf16x8* cbv = (const bf16x8*)cb;

    f32x16 acc;
    #pragma unroll
    for (int i = 0; i < 16; ++i) acc[i] = 0.f;

    i32x4 iv[BIV];
    bf16x8 bfr[BB][2];
    bf16x8 areg[2][2];

    #pragma unroll
    for (int v = -DI; v < NG; ++v) {
        // stage I: idx for group v+DI (nt: qidxs is single-use stream)
        if (v + DI < NG)
            iv[(v + DI) % BIV] = __builtin_nontemporal_load(
                (const i32x4*)(qrow + (v + DI) * 4));
        // stage G: gathers for group v+DG
        if (v + DG >= 0 && v + DG < NG) {
            i32x4 e = iv[(v + DG) % BIV];
            bfr[(v + DG) % BB][0] = cbv[h ? e[1] : e[0]];
            bfr[(v + DG) % BB][1] = cbv[h ? e[3] : e[2]];
        }
        // stage A: a-frags for group v+1 from LDS
        if (v + 1 >= 0 && v + 1 < NG) {
            const int T0 = 2 * (v + 1), T1 = T0 + 1;
            areg[(v + 1) & 1][0] = *(const bf16x8*)(xt +
                ((lc * CH + ((2 * T0 + h) ^ (lc & 7))) << 3));
            areg[(v + 1) & 1][1] = *(const bf16x8*)(xt +
                ((lc * CH + ((2 * T1 + h) ^ (lc & 7))) << 3));
        }
        __builtin_amdgcn_sched_barrier(0);   // loads may not sink past here
        // stage C: consume group v
        if (v >= 0) {
            acc = __builtin_amdgcn_mfma_f32_32x32x16_bf16(
                      areg[v & 1][0], bfr[v % BB][0], acc, 0, 0, 0);
            acc = __builtin_amdgcn_mfma_f32_32x32x16_bf16(
                      areg[v & 1][1], bfr[v % BB][1], acc, 0, 0, 0);
        }
    }

    // epilogue: bf16 partials
    __bf16* zp = zpart + ((size_t)ks * TOKENS) * OUT_F + n;
    #pragma unroll
    for (int r = 0; r < 16; ++r) {
        int m = (r & 3) + 4 * h + 8 * (r >> 2);
        zp[(size_t)m * OUT_F] = (__bf16)acc[r];
    }
}

// ------- kernel 3: out = fwht(sum_ks zpart)/sqrt(n) * SV * Wscale ----------
__global__ __launch_bounds__(256)
void zsum_kernel(const __bf16* __restrict__ zpart, const float* __restrict__ sv,
                 const float* __restrict__ wscale, float* __restrict__ out) {
    __shared__ float s[8192 + 256];
    const int t = blockIdx.x, tid = threadIdx.x;
    #pragma unroll
    for (int cc = 0; cc < 4; ++cc) {
        int col = cc * 2048 + tid * 8;
        float a[8] = {0.f, 0.f, 0.f, 0.f, 0.f, 0.f, 0.f, 0.f};
        #pragma unroll
        for (int ks = 0; ks < KSPLIT; ++ks) {
            bf16x8 v = *(const bf16x8*)(zpart +
                         ((size_t)(ks * TOKENS + t)) * OUT_F + col);
            #pragma unroll
            for (int j = 0; j < 8; ++j) a[j] += (float)v[j];
        }
        #pragma unroll
        for (int j = 0; j < 8; ++j) s[PAD(col + j)] = a[j];
    }
    __syncthreads();
    fwht8192_lds(s, tid);
    const float sc = INV_SQRT_8192 * wscale[0];
    #pragma unroll
    for (int i = tid; i < OUT_F; i += 256)
        out[t * OUT_F + i] = s[PAD(i)] * sc * sv[i];
}

extern "C" void kernel_launch(void* const* d_in, const int* in_sizes, int n_in,
                              void* d_out, int out_size, void* d_ws, size_t ws_size,
                              hipStream_t stream) {
    const float* x      = (const float*)d_in[0];   // (32, 8192)
    const float* cb     = (const float*)d_in[1];   // (65536, 8)
    const int*   qidxs  = (const int*)d_in[2];     // (8192, 1024)
    const float* su     = (const float*)d_in[3];   // (8192,)
    const float* sv     = (const float*)d_in[4];   // (8192,)
    const float* wscale = (const float*)d_in[5];   // scalar
    float* out = (float*)d_out;                    // (32, 8192) fp32

    char* ws = (char*)d_ws;
    __bf16* cb_bf16 = (__bf16*)ws;                               // 1 MB
    __bf16* xh      = (__bf16*)(ws + (1u << 20));                // 512 KB
    __bf16* zpart   = (__bf16*)(ws + (1u << 20) + (512u << 10)); // 8 MB bf16

    hipLaunchKernelGGL(prep_kernel, dim3(544), dim3(256), 0, stream,
                       cb, cb_bf16, x, su, xh);
    hipLaunchKernelGGL(qgemm_kernel, dim3(32 * KSPLIT), dim3(512), 0, stream,
                       qidxs, cb_bf16, xh, zpart);
    hipLaunchKernelGGL(zsum_kernel, dim3(TOKENS), dim3(256), 0, stream,
                       zpart, sv, wscale, out);
}